// Round 13
// baseline (525.790 us; speedup 1.0000x reference)
//
#include <hip/hip_runtime.h>

#define NN 200000
#define EE 6400000L
#define NCB 196          // coarse buckets of 1024 nodes
#define CAP 36864        // fixed bucket capacity (multiple of 4); mean 32653+pad<CAP
#define TILE 8192
#define NTILE 782        // ceil(6400000/8192)
#define QSTRIDE 200064   // quad-table stride in float4 units
#define GB64 3125        // node-groups per phase (64 nodes/group)

__device__ inline void f4add(float4& a, const float4 v) {
    a.x += v.x; a.y += v.y; a.z += v.z; a.w += v.w;
}

// ---------------------------------------------------------------------------
// Edge-index dtype hedge (int64 vs int32): if int64 with values < 2^31, every
// odd 32-bit word is zero. flag=1 -> int64 (word idx = elem<<1), 0 -> int32.
// Also initializes the per-bucket segment cursors gcur[b] = b*CAP.
// ---------------------------------------------------------------------------
__global__ void k_detect(const int* __restrict__ w, int* __restrict__ flag,
                         int* __restrict__ gcur) {
    __shared__ int any;
    if (threadIdx.x == 0) any = 0;
    __syncthreads();
    int found = 0;
    for (int i = threadIdx.x; i < 8192; i += 256)
        if (w[2 * i + 1] != 0) found = 1;
    if (found) atomicOr(&any, 1);
    if (threadIdx.x < NCB) gcur[threadIdx.x] = threadIdx.x * CAP;
    __syncthreads();
    if (threadIdx.x == 0) flag[0] = any ? 0 : 1;
}

// Partition into coarse buckets with tile-exclusive segments (fixed capacity).
// stage entry: src[17:0] | local_dst[27:18]
__global__ __launch_bounds__(256) void k_passA(
    const int* __restrict__ ew, const int* __restrict__ flag,
    int* __restrict__ gcur, unsigned* __restrict__ stage, long e) {
    __shared__ unsigned lv[TILE];
    __shared__ unsigned char lb[TILE];
    __shared__ int lh[NCB], lseg[NCB], lcur[NCB];
    for (int i = threadIdx.x; i < NCB; i += 256) { lh[i] = 0; lcur[i] = 0; }
    __syncthreads();
    long t0 = (long)blockIdx.x * TILE;
    int cnt = (int)min((long)TILE, e - t0);
    int shift = *flag;
    for (int i = threadIdx.x; i < cnt; i += 256) {
        int s = ew[(t0 + i) << shift];
        int d = ew[(EE + t0 + i) << shift];
        int b = d >> 10;
        lv[i] = (unsigned)s | ((unsigned)(d & 1023) << 18);
        lb[i] = (unsigned char)b;
        atomicAdd(&lh[b], 1);
    }
    __syncthreads();
    for (int i = threadIdx.x; i < NCB; i += 256)
        if (lh[i]) lseg[i] = atomicAdd(&gcur[i], lh[i]);
    __syncthreads();
    for (int i = threadIdx.x; i < cnt; i += 256) {
        int b = lb[i];
        int r = atomicAdd(&lcur[b], 1);
        stage[lseg[b] + r] = lv[i];
    }
}

// Per-bucket counting sort: stage (bucket-grouped) -> csr (node-grouped, src).
// Node segments padded to 4-entry (16B) alignment for uint4 csr loads.
// Emits odn = {offset, degree} and dis.
__global__ __launch_bounds__(1024) void k_sortB(
    const unsigned* __restrict__ stage, const int* __restrict__ gcur,
    float* __restrict__ dis, int2* __restrict__ odn,
    unsigned* __restrict__ csr, int n) {
    __shared__ int cnt[1024];
    __shared__ int cur[1024];
    __shared__ int wsum[16];
    int t = threadIdx.x, B = blockIdx.x;
    cnt[t] = 0;
    __syncthreads();
    int s0 = B * CAP, s1 = gcur[B];
    for (int i = s0 + t; i < s1; i += 1024)
        atomicAdd(&cnt[stage[i] >> 18], 1);
    __syncthreads();
    int c = cnt[t];
    int pc = (c + 3) & ~3;              // padded to 4 entries
    int lane = t & 63, w = t >> 6;
    int s = pc;
#pragma unroll
    for (int o = 1; o < 64; o <<= 1) {
        int u = __shfl_up(s, o, 64);
        if (lane >= o) s += u;
    }
    if (lane == 63) wsum[w] = s;
    __syncthreads();
    int add = 0;
    for (int k = 0; k < w; ++k) add += wsum[k];
    int excl = s - pc + add;
    cur[t] = excl;
    int node = B * 1024 + t;
    if (node < n) {
        odn[node] = make_int2(s0 + excl, c);
        dis[node] = rsqrtf((float)(c + 1));
    }
    __syncthreads();
    for (int i = s0 + t; i < s1; i += 1024) {
        unsigned v = stage[i];
        int pos = s0 + atomicAdd(&cur[v >> 18], 1);
        csr[pos] = v & 0x3FFFF;
    }
}

// Layer 1 matmul: hws = dis ⊙ (x @ W1), written QUAD-MAJOR.
__global__ __launch_bounds__(256) void k_mm1(
    const float* __restrict__ x, const float* __restrict__ W,
    const float* __restrict__ dis, float4* __restrict__ outq, int n) {
    __shared__ float Wl[256 * 16];
    int t = threadIdx.x;
#pragma unroll
    for (int i = 0; i < 4; ++i)
        ((float4*)Wl)[t + i * 256] = ((const float4*)W)[t + i * 256];
    __syncthreads();

    int node = blockIdx.x * 256 + t;
    if (node >= n) return;

    const float4* xr = (const float4*)(x + (long)node * 256);
    float acc[16];
#pragma unroll
    for (int o = 0; o < 16; ++o) acc[o] = 0.f;

#pragma unroll 8
    for (int kk = 0; kk < 64; ++kk) {
        float4 xv = xr[kk];
#pragma unroll
        for (int q = 0; q < 4; ++q) {
            float xs = (q == 0) ? xv.x : (q == 1) ? xv.y : (q == 2) ? xv.z : xv.w;
            const float4* wr = (const float4*)&Wl[(kk * 4 + q) * 16];
#pragma unroll
            for (int oo = 0; oo < 4; ++oo) {
                float4 wv = wr[oo];
                acc[oo * 4 + 0] = fmaf(xs, wv.x, acc[oo * 4 + 0]);
                acc[oo * 4 + 1] = fmaf(xs, wv.y, acc[oo * 4 + 1]);
                acc[oo * 4 + 2] = fmaf(xs, wv.z, acc[oo * 4 + 2]);
                acc[oo * 4 + 3] = fmaf(xs, wv.w, acc[oo * 4 + 3]);
            }
        }
    }
    float dv = dis[node];
#pragma unroll
    for (int q = 0; q < 4; ++q)
        outq[q * QSTRIDE + node] = make_float4(acc[q * 4] * dv, acc[q * 4 + 1] * dv,
                                               acc[q * 4 + 2] * dv, acc[q * 4 + 3] * dv);
}

// 16x16 matmul: hws = dis ⊙ (h @ W), quad-major in AND out.
__global__ __launch_bounds__(256) void k_mm2(
    const float4* __restrict__ hq, const float* __restrict__ W,
    const float* __restrict__ dis, float4* __restrict__ outq, int n) {
    __shared__ float Wl[256];
    if (threadIdx.x < 64) ((float4*)Wl)[threadIdx.x] = ((const float4*)W)[threadIdx.x];
    __syncthreads();
    int node = blockIdx.x * 256 + threadIdx.x;
    if (node >= n) return;
    float hv[16];
#pragma unroll
    for (int i = 0; i < 4; ++i) {
        float4 v = hq[i * QSTRIDE + node];
        hv[i * 4 + 0] = v.x; hv[i * 4 + 1] = v.y; hv[i * 4 + 2] = v.z; hv[i * 4 + 3] = v.w;
    }
    float acc[16];
#pragma unroll
    for (int o = 0; o < 16; ++o) acc[o] = 0.f;
#pragma unroll
    for (int k = 0; k < 16; ++k) {
        float xs = hv[k];
#pragma unroll
        for (int o = 0; o < 16; ++o) acc[o] = fmaf(xs, Wl[k * 16 + o], acc[o]);
    }
    float dv = dis[node];
#pragma unroll
    for (int q = 0; q < 4; ++q)
        outq[q * QSTRIDE + node] = make_float4(acc[q * 4] * dv, acc[q * 4 + 1] * dv,
                                               acc[q * 4 + 2] * dv, acc[q * 4 + 3] * dv);
}

// 16x1 matmul: hws3 = dis ⊙ (h @ W3), quad-major in, scalar out.
__global__ __launch_bounds__(256) void k_mm3(
    const float4* __restrict__ hq, const float* __restrict__ W,
    const float* __restrict__ dis, float* __restrict__ hws3, int n) {
    int node = blockIdx.x * 256 + threadIdx.x;
    if (node >= n) return;
    float acc = 0.f;
#pragma unroll
    for (int i = 0; i < 4; ++i) {
        float4 v = hq[i * QSTRIDE + node];
        acc = fmaf(v.x, W[i * 4 + 0], acc);
        acc = fmaf(v.y, W[i * 4 + 1], acc);
        acc = fmaf(v.z, W[i * 4 + 2], acc);
        acc = fmaf(v.w, W[i * 4 + 3], acc);
    }
    hws3[node] = acc * dis[node];
}

// Quad-phased gather, high-MLP form: 4 lanes/node; lane j owns csr chunks
// {4j, 4j+16, ...}, loads each as uint4 (4 entries/lane-load) and issues 4
// independent 16B gathers; dual-chunk unroll keeps ~2 csr + 8 gathers in
// flight per lane. Phase q touches only the 3.2MB quad-q table (L2-resident).
template <int RELU>
__global__ __launch_bounds__(256) void k_g16q(
    const int2* __restrict__ odn, const unsigned* __restrict__ csr,
    const float* __restrict__ dis, const float4* __restrict__ tabq,
    const float* __restrict__ b, float4* __restrict__ outq, int n) {
    int bid = blockIdx.x;
    int q = bid / GB64;                 // phase-major
    int g = bid - q * GB64;
    int t = threadIdx.x;
    int node = g * 64 + (t >> 2);
    int j = t & 3;
    if (node >= n) return;
    const float4* tab = tabq + (long)q * QSTRIDE;
    int2 od = odn[node];
    int s0 = od.x, dg = od.y;
    float4 aA = make_float4(0.f, 0.f, 0.f, 0.f);
    float4 aB = make_float4(0.f, 0.f, 0.f, 0.f);
    int c0 = 4 * j;
    // dual-chunk: 2 uint4 csr loads + 8 gathers in flight
    for (; c0 + 20 <= dg; c0 += 32) {
        uint4 eL = *(const uint4*)(csr + s0 + c0);
        uint4 eH = *(const uint4*)(csr + s0 + c0 + 16);
        f4add(aA, tab[eL.x]); f4add(aB, tab[eH.x]);
        f4add(aA, tab[eL.y]); f4add(aB, tab[eH.y]);
        f4add(aA, tab[eL.z]); f4add(aB, tab[eH.z]);
        f4add(aA, tab[eL.w]); f4add(aB, tab[eH.w]);
    }
    for (; c0 + 4 <= dg; c0 += 16) {
        uint4 e = *(const uint4*)(csr + s0 + c0);
        f4add(aA, tab[e.x]); f4add(aA, tab[e.y]);
        f4add(aA, tab[e.z]); f4add(aA, tab[e.w]);
    }
    if ((dg & 3) && j == ((dg >> 2) & 3)) {        // scalar tail, owner lane
        for (int k2 = dg & ~3; k2 < dg; ++k2)
            f4add(aA, tab[csr[s0 + k2]]);
    }
    f4add(aA, aB);
#pragma unroll
    for (int o = 1; o <= 2; o <<= 1) {
        aA.x += __shfl_xor(aA.x, o, 4);
        aA.y += __shfl_xor(aA.y, o, 4);
        aA.z += __shfl_xor(aA.z, o, 4);
        aA.w += __shfl_xor(aA.w, o, 4);
    }
    if (j == 0) {
        f4add(aA, tab[node]);           // self-loop (pre-scaled)
        float dv = dis[node];
        float4 bb = ((const float4*)b)[q];
        float4 r = make_float4(fmaf(dv, aA.x, bb.x), fmaf(dv, aA.y, bb.y),
                               fmaf(dv, aA.z, bb.z), fmaf(dv, aA.w, bb.w));
        if (RELU) {
            r.x = fmaxf(r.x, 0.f); r.y = fmaxf(r.y, 0.f);
            r.z = fmaxf(r.z, 0.f); r.w = fmaxf(r.w, 0.f);
        }
        outq[(long)q * QSTRIDE + node] = r;
    }
}

// Gather-aggregate, 1 channel from the 800KB pre-scaled table (L2-resident).
__global__ __launch_bounds__(256) void k_g1(
    const int2* __restrict__ odn, const unsigned* __restrict__ csr,
    const float* __restrict__ dis, const float* __restrict__ hws3,
    const float* __restrict__ b, float* __restrict__ out, int n) {
    int t = threadIdx.x;
    int node = blockIdx.x * 16 + (t >> 4);
    int ln = t & 15;
    if (node >= n) return;
    int2 od = odn[node];
    int s0 = od.x, dg = od.y;
    float acc = 0.f;
    for (int k = ln; k < dg; k += 16)
        acc += hws3[csr[s0 + k]];
#pragma unroll
    for (int o = 8; o >= 1; o >>= 1) acc += __shfl_down(acc, o, 16);
    if (ln == 0)
        out[node] = fmaf(dis[node], acc + hws3[node], b[0]);
}

extern "C" void kernel_launch(void* const* d_in, const int* in_sizes, int n_in,
                              void* d_out, int out_size, void* d_ws, size_t ws_size,
                              hipStream_t stream) {
    const float* x  = (const float*)d_in[0];
    const int*   ew = (const int*)d_in[1];
    const float* W1 = (const float*)d_in[2];
    const float* b1 = (const float*)d_in[3];
    const float* W2 = (const float*)d_in[4];
    const float* b2 = (const float*)d_in[5];
    const float* W3 = (const float*)d_in[6];
    const float* b3 = (const float*)d_in[7];
    float* out = (float*)d_out;

    // Workspace (4-byte words), ~90 MB. bufA/bufB are quad-major float4 tables.
    unsigned* stage = (unsigned*)d_ws;               // NCB*CAP = 7,225,344
    unsigned* csr   = stage + (long)NCB * CAP;       // 7,225,344
    int*      gcur  = (int*)(csr + (long)NCB * CAP); // 256
    int*      flag  = gcur + 256;                    // 16
    int2*     odn   = (int2*)(flag + 16);            // 200,704 int2
    float*    dis   = (float*)(odn + 200704);        // 200,704
    float4*   bufA  = (float4*)(dis + 200704);       // 4*QSTRIDE float4 (hws / +hws3)
    float4*   bufB  = bufA + 4 * QSTRIDE;            // 4*QSTRIDE float4 (h)

    const int n = NN;
    const long e = EE;
    int nb = (n + 255) / 256;   // 782
    int g1b = (n + 15) / 16;    // 12500

    // detect + cursor init -> partition -> per-bucket sort
    k_detect<<<1, 256, 0, stream>>>(ew, flag, gcur);
    k_passA<<<NTILE, 256, 0, stream>>>(ew, flag, gcur, stage, e);
    k_sortB<<<NCB, 1024, 0, stream>>>(stage, gcur, dis, odn, csr, n);

    // Layer 1
    k_mm1<<<nb, 256, 0, stream>>>(x, W1, dis, bufA, n);
    k_g16q<1><<<4 * GB64, 256, 0, stream>>>(odn, csr, dis, bufA, b1, bufB, n);
    // Layer 2
    k_mm2<<<nb, 256, 0, stream>>>(bufB, W2, dis, bufA, n);
    k_g16q<1><<<4 * GB64, 256, 0, stream>>>(odn, csr, dis, bufA, b2, bufB, n);
    // Layer 3
    k_mm3<<<nb, 256, 0, stream>>>(bufB, W3, dis, (float*)bufA, n);
    k_g1<<<g1b, 256, 0, stream>>>(odn, csr, dis, (const float*)bufA, b3, out, n);
}

// Round 14
// 454.027 us; speedup vs baseline: 1.1581x; 1.1581x over previous
//
#include <hip/hip_runtime.h>

#define NN 200000
#define EE 6400000L
#define NCB 196          // coarse buckets of 1024 nodes
#define CAP 36864        // fixed bucket capacity (multiple of 4); mean 32653 + 6σ + pad < CAP
#define TILE 8192
#define NTILE 782        // ceil(6400000/8192)

__device__ inline void f4add(float4& a, const float4 v) {
    a.x += v.x; a.y += v.y; a.z += v.z; a.w += v.w;
}

// ---------------------------------------------------------------------------
// Edge-index dtype hedge (int64 vs int32): if int64 with values < 2^31, every
// odd 32-bit word is zero. flag=1 -> int64 (word idx = elem<<1), 0 -> int32.
// Also initializes the per-bucket segment cursors gcur[b] = b*CAP.
// ---------------------------------------------------------------------------
__global__ void k_detect(const int* __restrict__ w, int* __restrict__ flag,
                         int* __restrict__ gcur) {
    __shared__ int any;
    if (threadIdx.x == 0) any = 0;
    __syncthreads();
    int found = 0;
    for (int i = threadIdx.x; i < 8192; i += 256)
        if (w[2 * i + 1] != 0) found = 1;
    if (found) atomicOr(&any, 1);
    if (threadIdx.x < NCB) gcur[threadIdx.x] = threadIdx.x * CAP;
    __syncthreads();
    if (threadIdx.x == 0) flag[0] = any ? 0 : 1;
}

// Partition into coarse buckets with tile-exclusive segments (fixed capacity).
// stage entry: src[17:0] | local_dst[27:18]
__global__ __launch_bounds__(256) void k_passA(
    const int* __restrict__ ew, const int* __restrict__ flag,
    int* __restrict__ gcur, unsigned* __restrict__ stage, long e) {
    __shared__ unsigned lv[TILE];
    __shared__ unsigned char lb[TILE];
    __shared__ int lh[NCB], lseg[NCB], lcur[NCB];
    for (int i = threadIdx.x; i < NCB; i += 256) { lh[i] = 0; lcur[i] = 0; }
    __syncthreads();
    long t0 = (long)blockIdx.x * TILE;
    int cnt = (int)min((long)TILE, e - t0);
    int shift = *flag;
    for (int i = threadIdx.x; i < cnt; i += 256) {
        int s = ew[(t0 + i) << shift];
        int d = ew[(EE + t0 + i) << shift];
        int b = d >> 10;
        lv[i] = (unsigned)s | ((unsigned)(d & 1023) << 18);
        lb[i] = (unsigned char)b;
        atomicAdd(&lh[b], 1);
    }
    __syncthreads();
    for (int i = threadIdx.x; i < NCB; i += 256)
        if (lh[i]) lseg[i] = atomicAdd(&gcur[i], lh[i]);
    __syncthreads();
    for (int i = threadIdx.x; i < cnt; i += 256) {
        int b = lb[i];
        int r = atomicAdd(&lcur[b], 1);
        stage[lseg[b] + r] = lv[i];
    }
}

// Per-bucket counting sort: stage (bucket-grouped) -> csr (node-grouped, src).
// Node segments padded to 4-entry (16B) alignment for uint4 csr loads.
// Emits odn = {offset, degree} and dis.
__global__ __launch_bounds__(1024) void k_sortB(
    const unsigned* __restrict__ stage, const int* __restrict__ gcur,
    float* __restrict__ dis, int2* __restrict__ odn,
    unsigned* __restrict__ csr, int n) {
    __shared__ int cnt[1024];
    __shared__ int cur[1024];
    __shared__ int wsum[16];
    int t = threadIdx.x, B = blockIdx.x;
    cnt[t] = 0;
    __syncthreads();
    int s0 = B * CAP, s1 = gcur[B];
    for (int i = s0 + t; i < s1; i += 1024)
        atomicAdd(&cnt[stage[i] >> 18], 1);
    __syncthreads();
    int c = cnt[t];
    int pc = (c + 3) & ~3;              // padded to 4 entries (16B)
    int lane = t & 63, w = t >> 6;
    int s = pc;
#pragma unroll
    for (int o = 1; o < 64; o <<= 1) {
        int u = __shfl_up(s, o, 64);
        if (lane >= o) s += u;
    }
    if (lane == 63) wsum[w] = s;
    __syncthreads();
    int add = 0;
    for (int k = 0; k < w; ++k) add += wsum[k];
    int excl = s - pc + add;
    cur[t] = excl;
    int node = B * 1024 + t;
    if (node < n) {
        odn[node] = make_int2(s0 + excl, c);
        dis[node] = rsqrtf((float)(c + 1));
    }
    __syncthreads();
    for (int i = s0 + t; i < s1; i += 1024) {
        unsigned v = stage[i];
        int pos = s0 + atomicAdd(&cur[v >> 18], 1);
        csr[pos] = v & 0x3FFFF;
    }
}

// Layer 1 matmul: hws = dis ⊙ (x @ W1), row-major float4 quads.
__global__ __launch_bounds__(256) void k_mm1(
    const float* __restrict__ x, const float* __restrict__ W,
    const float* __restrict__ dis, float4* __restrict__ outr, int n) {
    __shared__ float Wl[256 * 16];
    int t = threadIdx.x;
#pragma unroll
    for (int i = 0; i < 4; ++i)
        ((float4*)Wl)[t + i * 256] = ((const float4*)W)[t + i * 256];
    __syncthreads();

    int node = blockIdx.x * 256 + t;
    if (node >= n) return;

    const float4* xr = (const float4*)(x + (long)node * 256);
    float acc[16];
#pragma unroll
    for (int o = 0; o < 16; ++o) acc[o] = 0.f;

#pragma unroll 8
    for (int kk = 0; kk < 64; ++kk) {
        float4 xv = xr[kk];
#pragma unroll
        for (int q = 0; q < 4; ++q) {
            float xs = (q == 0) ? xv.x : (q == 1) ? xv.y : (q == 2) ? xv.z : xv.w;
            const float4* wr = (const float4*)&Wl[(kk * 4 + q) * 16];
#pragma unroll
            for (int oo = 0; oo < 4; ++oo) {
                float4 wv = wr[oo];
                acc[oo * 4 + 0] = fmaf(xs, wv.x, acc[oo * 4 + 0]);
                acc[oo * 4 + 1] = fmaf(xs, wv.y, acc[oo * 4 + 1]);
                acc[oo * 4 + 2] = fmaf(xs, wv.z, acc[oo * 4 + 2]);
                acc[oo * 4 + 3] = fmaf(xs, wv.w, acc[oo * 4 + 3]);
            }
        }
    }
    float dv = dis[node];
#pragma unroll
    for (int q = 0; q < 4; ++q)
        outr[node * 4 + q] = make_float4(acc[q * 4] * dv, acc[q * 4 + 1] * dv,
                                         acc[q * 4 + 2] * dv, acc[q * 4 + 3] * dv);
}

// 16x16 matmul: hws = dis ⊙ (h @ W), row-major in and out.
__global__ __launch_bounds__(256) void k_mm2(
    const float4* __restrict__ hr, const float* __restrict__ W,
    const float* __restrict__ dis, float4* __restrict__ outr, int n) {
    __shared__ float Wl[256];
    if (threadIdx.x < 64) ((float4*)Wl)[threadIdx.x] = ((const float4*)W)[threadIdx.x];
    __syncthreads();
    int node = blockIdx.x * 256 + threadIdx.x;
    if (node >= n) return;
    float hv[16];
#pragma unroll
    for (int i = 0; i < 4; ++i) {
        float4 v = hr[node * 4 + i];
        hv[i * 4 + 0] = v.x; hv[i * 4 + 1] = v.y; hv[i * 4 + 2] = v.z; hv[i * 4 + 3] = v.w;
    }
    float acc[16];
#pragma unroll
    for (int o = 0; o < 16; ++o) acc[o] = 0.f;
#pragma unroll
    for (int k = 0; k < 16; ++k) {
        float xs = hv[k];
#pragma unroll
        for (int o = 0; o < 16; ++o) acc[o] = fmaf(xs, Wl[k * 16 + o], acc[o]);
    }
    float dv = dis[node];
#pragma unroll
    for (int q = 0; q < 4; ++q)
        outr[node * 4 + q] = make_float4(acc[q * 4] * dv, acc[q * 4 + 1] * dv,
                                         acc[q * 4 + 2] * dv, acc[q * 4 + 3] * dv);
}

// 16x1 matmul: hws3 = dis ⊙ (h @ W3), row-major in, scalar out.
__global__ __launch_bounds__(256) void k_mm3(
    const float4* __restrict__ hr, const float* __restrict__ W,
    const float* __restrict__ dis, float* __restrict__ hws3, int n) {
    int node = blockIdx.x * 256 + threadIdx.x;
    if (node >= n) return;
    float acc = 0.f;
#pragma unroll
    for (int i = 0; i < 4; ++i) {
        float4 v = hr[node * 4 + i];
        acc = fmaf(v.x, W[i * 4 + 0], acc);
        acc = fmaf(v.y, W[i * 4 + 1], acc);
        acc = fmaf(v.z, W[i * 4 + 2], acc);
        acc = fmaf(v.w, W[i * 4 + 3], acc);
    }
    hws3[node] = acc * dis[node];
}

// Gather-aggregate, 16 channels, row-major table. 4 lanes per node; lane j
// owns quad j of EVERY edge row (4 lanes consume the full 64B line together;
// no cross-lane reduce — lane j writes quad j). csr is loaded as a
// lane-uniform uint4 (1 broadcast request per 4 edges); dual-chunk unroll
// keeps 8 gathers + 2 csr loads in flight per lane.
// h[i,:] = relu?( b + dv*( sum_e hws[src_e,:] + hws[i,:] ) )
template <int RELU>
__global__ __launch_bounds__(256) void k_g16(
    const int2* __restrict__ odn, const unsigned* __restrict__ csr,
    const float* __restrict__ dis, const float4* __restrict__ tab,
    const float* __restrict__ b, float4* __restrict__ outr, int n) {
    int t = threadIdx.x;
    int node = blockIdx.x * 64 + (t >> 2);
    int j = t & 3;
    if (node >= n) return;
    int2 od = odn[node];
    int s0 = od.x, dg = od.y;
    float4 aA = make_float4(0.f, 0.f, 0.f, 0.f);
    float4 aB = make_float4(0.f, 0.f, 0.f, 0.f);
    int k = 0;
    for (; k + 8 <= dg; k += 8) {
        uint4 eL = *(const uint4*)(csr + s0 + k);
        uint4 eH = *(const uint4*)(csr + s0 + k + 4);
        f4add(aA, tab[eL.x * 4 + j]);
        f4add(aB, tab[eH.x * 4 + j]);
        f4add(aA, tab[eL.y * 4 + j]);
        f4add(aB, tab[eH.y * 4 + j]);
        f4add(aA, tab[eL.z * 4 + j]);
        f4add(aB, tab[eH.z * 4 + j]);
        f4add(aA, tab[eL.w * 4 + j]);
        f4add(aB, tab[eH.w * 4 + j]);
    }
    if (k + 4 <= dg) {
        uint4 e = *(const uint4*)(csr + s0 + k);
        f4add(aA, tab[e.x * 4 + j]);
        f4add(aB, tab[e.y * 4 + j]);
        f4add(aA, tab[e.z * 4 + j]);
        f4add(aB, tab[e.w * 4 + j]);
        k += 4;
    }
    for (; k < dg; ++k)                          // all 4 lanes: each edge needs all quads
        f4add(aA, tab[csr[s0 + k] * 4 + j]);
    f4add(aA, aB);
    f4add(aA, tab[node * 4 + j]);                // self-loop (pre-scaled)
    float dv = dis[node];
    float4 bb = ((const float4*)b)[j];
    float4 r = make_float4(fmaf(dv, aA.x, bb.x), fmaf(dv, aA.y, bb.y),
                           fmaf(dv, aA.z, bb.z), fmaf(dv, aA.w, bb.w));
    if (RELU) {
        r.x = fmaxf(r.x, 0.f); r.y = fmaxf(r.y, 0.f);
        r.z = fmaxf(r.z, 0.f); r.w = fmaxf(r.w, 0.f);
    }
    outr[node * 4 + j] = r;
}

// Gather-aggregate, 1 channel from the 800KB pre-scaled table (L2-resident).
__global__ __launch_bounds__(256) void k_g1(
    const int2* __restrict__ odn, const unsigned* __restrict__ csr,
    const float* __restrict__ dis, const float* __restrict__ hws3,
    const float* __restrict__ b, float* __restrict__ out, int n) {
    int t = threadIdx.x;
    int node = blockIdx.x * 16 + (t >> 4);
    int ln = t & 15;
    if (node >= n) return;
    int2 od = odn[node];
    int s0 = od.x, dg = od.y;
    float acc = 0.f;
    for (int k = ln; k < dg; k += 16)
        acc += hws3[csr[s0 + k]];
#pragma unroll
    for (int o = 8; o >= 1; o >>= 1) acc += __shfl_down(acc, o, 16);
    if (ln == 0)
        out[node] = fmaf(dis[node], acc + hws3[node], b[0]);
}

extern "C" void kernel_launch(void* const* d_in, const int* in_sizes, int n_in,
                              void* d_out, int out_size, void* d_ws, size_t ws_size,
                              hipStream_t stream) {
    const float* x  = (const float*)d_in[0];
    const int*   ew = (const int*)d_in[1];
    const float* W1 = (const float*)d_in[2];
    const float* b1 = (const float*)d_in[3];
    const float* W2 = (const float*)d_in[4];
    const float* b2 = (const float*)d_in[5];
    const float* W3 = (const float*)d_in[6];
    const float* b3 = (const float*)d_in[7];
    float* out = (float*)d_out;

    // Workspace (4-byte words), ~90 MB. bufA/bufB are row-major [N][16] tables.
    unsigned* stage = (unsigned*)d_ws;               // NCB*CAP = 7,225,344
    unsigned* csr   = stage + (long)NCB * CAP;       // 7,225,344
    int*      gcur  = (int*)(csr + (long)NCB * CAP); // 256
    int*      flag  = gcur + 256;                    // 16
    int2*     odn   = (int2*)(flag + 16);            // 200,704 int2
    float*    dis   = (float*)(odn + 200704);        // 200,704
    float4*   bufA  = (float4*)(dis + 200704);       // 4*200,064 float4 (hws / hws3)
    float4*   bufB  = bufA + 4 * 200064;             // 4*200,064 float4 (h)

    const int n = NN;
    const long e = EE;
    int nb = (n + 255) / 256;   // 782
    int gb = (n + 63) / 64;     // 3125 (k_g16: 64 nodes/block)
    int g1b = (n + 15) / 16;    // 12500

    // detect + cursor init -> partition -> per-bucket sort
    k_detect<<<1, 256, 0, stream>>>(ew, flag, gcur);
    k_passA<<<NTILE, 256, 0, stream>>>(ew, flag, gcur, stage, e);
    k_sortB<<<NCB, 1024, 0, stream>>>(stage, gcur, dis, odn, csr, n);

    // Layer 1
    k_mm1<<<nb, 256, 0, stream>>>(x, W1, dis, bufA, n);
    k_g16<1><<<gb, 256, 0, stream>>>(odn, csr, dis, bufA, b1, bufB, n);
    // Layer 2
    k_mm2<<<nb, 256, 0, stream>>>(bufB, W2, dis, bufA, n);
    k_g16<1><<<gb, 256, 0, stream>>>(odn, csr, dis, bufA, b2, bufB, n);
    // Layer 3
    k_mm3<<<nb, 256, 0, stream>>>(bufB, W3, dis, (float*)bufA, n);
    k_g1<<<g1b, 256, 0, stream>>>(odn, csr, dis, (const float*)bufA, b3, out, n);
}

// Round 15
// 439.950 us; speedup vs baseline: 1.1951x; 1.0320x over previous
//
#include <hip/hip_runtime.h>

#define NN 200000
#define EE 6400000L
#define NCB 196          // coarse buckets of 1024 nodes
#define CAP 36864        // fixed bucket capacity; mean 32653 + 6σ + pad < CAP
#define TILE 8192
#define NTILE 782        // ceil(6400000/8192)

__device__ inline void f4add(float4& a, const float4 v) {
    a.x += v.x; a.y += v.y; a.z += v.z; a.w += v.w;
}

// LDS union for the fused partition∥matmul kernel (43,312 B -> 3 blocks/CU)
union SMem {
    struct {
        unsigned lv[TILE];
        unsigned char lb[TILE];
        int lh[NCB], lseg[NCB], lcur[NCB];
    } p;
    float wl[256 * 16];
};

// ---------------------------------------------------------------------------
// Edge-index dtype hedge (int64 vs int32): if int64 with values < 2^31, every
// odd 32-bit word is zero. flag=1 -> int64 (word idx = elem<<1), 0 -> int32.
// Also initializes the per-bucket segment cursors gcur[b] = b*CAP.
// ---------------------------------------------------------------------------
__global__ void k_detect(const int* __restrict__ w, int* __restrict__ flag,
                         int* __restrict__ gcur) {
    __shared__ int any;
    if (threadIdx.x == 0) any = 0;
    __syncthreads();
    int found = 0;
    for (int i = threadIdx.x; i < 8192; i += 256)
        if (w[2 * i + 1] != 0) found = 1;
    if (found) atomicOr(&any, 1);
    if (threadIdx.x < NCB) gcur[threadIdx.x] = threadIdx.x * CAP;
    __syncthreads();
    if (threadIdx.x == 0) flag[0] = any ? 0 : 1;
}

// Fused kernel: even blocks partition edges into bucket segments (passA),
// odd blocks compute UNSCALED hw1 = x @ W1 (mm1). Independent work, mixed
// pipes (memory+LDS-atomics vs FMA) -> co-resident overlap.
__global__ __launch_bounds__(256) void k_fused(
    const int* __restrict__ ew, const int* __restrict__ flag,
    int* __restrict__ gcur, unsigned* __restrict__ stage,
    const float* __restrict__ x, const float* __restrict__ W1,
    float4* __restrict__ hw1, long e, int n) {
    __shared__ SMem sm;
    int t = threadIdx.x;
    int role = blockIdx.x & 1;
    int idx = blockIdx.x >> 1;

    if (role == 0) {
        // ---- passA: tile-exclusive segmented partition ----
        for (int i = t; i < NCB; i += 256) { sm.p.lh[i] = 0; sm.p.lcur[i] = 0; }
        __syncthreads();
        long t0 = (long)idx * TILE;
        int cnt = (int)min((long)TILE, e - t0);
        int shift = *flag;
        for (int i = t; i < cnt; i += 256) {
            int s = ew[(t0 + i) << shift];
            int d = ew[(EE + t0 + i) << shift];
            int b = d >> 10;
            sm.p.lv[i] = (unsigned)s | ((unsigned)(d & 1023) << 18);
            sm.p.lb[i] = (unsigned char)b;
            atomicAdd(&sm.p.lh[b], 1);
        }
        __syncthreads();
        for (int i = t; i < NCB; i += 256)
            if (sm.p.lh[i]) sm.p.lseg[i] = atomicAdd(&gcur[i], sm.p.lh[i]);
        __syncthreads();
        for (int i = t; i < cnt; i += 256) {
            int b = sm.p.lb[i];
            int r = atomicAdd(&sm.p.lcur[b], 1);
            stage[sm.p.lseg[b] + r] = sm.p.lv[i];
        }
    } else {
        // ---- mm1: hw1 = x @ W1 (unscaled; dis applied in k_sortB) ----
#pragma unroll
        for (int i = 0; i < 4; ++i)
            ((float4*)sm.wl)[t + i * 256] = ((const float4*)W1)[t + i * 256];
        __syncthreads();
        int node = idx * 256 + t;
        if (node >= n) return;
        const float4* xr = (const float4*)(x + (long)node * 256);
        float acc[16];
#pragma unroll
        for (int o = 0; o < 16; ++o) acc[o] = 0.f;
#pragma unroll 8
        for (int kk = 0; kk < 64; ++kk) {
            float4 xv = xr[kk];
#pragma unroll
            for (int q = 0; q < 4; ++q) {
                float xs = (q == 0) ? xv.x : (q == 1) ? xv.y : (q == 2) ? xv.z : xv.w;
                const float4* wr = (const float4*)&sm.wl[(kk * 4 + q) * 16];
#pragma unroll
                for (int oo = 0; oo < 4; ++oo) {
                    float4 wv = wr[oo];
                    acc[oo * 4 + 0] = fmaf(xs, wv.x, acc[oo * 4 + 0]);
                    acc[oo * 4 + 1] = fmaf(xs, wv.y, acc[oo * 4 + 1]);
                    acc[oo * 4 + 2] = fmaf(xs, wv.z, acc[oo * 4 + 2]);
                    acc[oo * 4 + 3] = fmaf(xs, wv.w, acc[oo * 4 + 3]);
                }
            }
        }
#pragma unroll
        for (int q = 0; q < 4; ++q)
            hw1[(long)node * 4 + q] = make_float4(acc[q * 4], acc[q * 4 + 1],
                                                  acc[q * 4 + 2], acc[q * 4 + 3]);
    }
}

// Per-bucket counting sort + node metadata + in-place dis-scaling of hw1.
// stage (bucket-grouped) -> csr (node-grouped, src only, 16B-padded segments).
__global__ __launch_bounds__(1024) void k_sortB(
    const unsigned* __restrict__ stage, const int* __restrict__ gcur,
    float* __restrict__ dis, int2* __restrict__ odn,
    unsigned* __restrict__ csr, float4* __restrict__ hw1, int n) {
    __shared__ int cnt[1024];
    __shared__ int cur[1024];
    __shared__ int wsum[16];
    int t = threadIdx.x, B = blockIdx.x;
    cnt[t] = 0;
    __syncthreads();
    int s0 = B * CAP, s1 = gcur[B];
    for (int i = s0 + t; i < s1; i += 1024)
        atomicAdd(&cnt[stage[i] >> 18], 1);
    __syncthreads();
    int c = cnt[t];
    int pc = (c + 3) & ~3;              // pad to 4 entries (16B) for uint4 loads
    int lane = t & 63, w = t >> 6;
    int s = pc;
#pragma unroll
    for (int o = 1; o < 64; o <<= 1) {
        int u = __shfl_up(s, o, 64);
        if (lane >= o) s += u;
    }
    if (lane == 63) wsum[w] = s;
    __syncthreads();
    int add = 0;
    for (int k = 0; k < w; ++k) add += wsum[k];
    int excl = s - pc + add;
    cur[t] = excl;
    int node = B * 1024 + t;
    if (node < n) {
        float dv = rsqrtf((float)(c + 1));
        odn[node] = make_int2(s0 + excl, c);
        dis[node] = dv;
        float4* row = hw1 + (long)node * 4;
#pragma unroll
        for (int q = 0; q < 4; ++q) {
            float4 v = row[q];
            row[q] = make_float4(v.x * dv, v.y * dv, v.z * dv, v.w * dv);
        }
    }
    __syncthreads();
    for (int i = s0 + t; i < s1; i += 1024) {
        unsigned v = stage[i];
        int pos = s0 + atomicAdd(&cur[v >> 18], 1);
        csr[pos] = v & 0x3FFFF;
    }
}

// Layer-1 gather + relu + FUSED mm2 + scale. 4 lanes/node, 64 nodes/block
// (grid exactly n/64 -> barrier-safe). Gather as round 14 (lane-uniform uint4
// csr, dual-chunk, full 64B row per node). Epilogue: h1 quad -> LDS
// (stride 17), barrier, each lane computes quad j of dis*(h1@W2).
__global__ __launch_bounds__(256) void k_g16a(
    const int2* __restrict__ odn, const unsigned* __restrict__ csr,
    const float* __restrict__ dis, const float4* __restrict__ tab,
    const float* __restrict__ b1v, const float* __restrict__ W2,
    float4* __restrict__ out2) {
    __shared__ float h1s[64 * 17];
    __shared__ float W2l[256];
    int t = threadIdx.x;
    if (t < 64) ((float4*)W2l)[t] = ((const float4*)W2)[t];
    int node = blockIdx.x * 64 + (t >> 2);
    int j = t & 3;
    int2 od = odn[node];
    int s0 = od.x, dg = od.y;
    float4 aA = make_float4(0.f, 0.f, 0.f, 0.f);
    float4 aB = make_float4(0.f, 0.f, 0.f, 0.f);
    int k = 0;
    for (; k + 8 <= dg; k += 8) {
        uint4 eL = *(const uint4*)(csr + s0 + k);
        uint4 eH = *(const uint4*)(csr + s0 + k + 4);
        f4add(aA, tab[eL.x * 4 + j]);
        f4add(aB, tab[eH.x * 4 + j]);
        f4add(aA, tab[eL.y * 4 + j]);
        f4add(aB, tab[eH.y * 4 + j]);
        f4add(aA, tab[eL.z * 4 + j]);
        f4add(aB, tab[eH.z * 4 + j]);
        f4add(aA, tab[eL.w * 4 + j]);
        f4add(aB, tab[eH.w * 4 + j]);
    }
    if (k + 4 <= dg) {
        uint4 e = *(const uint4*)(csr + s0 + k);
        f4add(aA, tab[e.x * 4 + j]);
        f4add(aB, tab[e.y * 4 + j]);
        f4add(aA, tab[e.z * 4 + j]);
        f4add(aB, tab[e.w * 4 + j]);
        k += 4;
    }
    for (; k < dg; ++k)
        f4add(aA, tab[csr[s0 + k] * 4 + j]);
    f4add(aA, aB);
    f4add(aA, tab[node * 4 + j]);               // self-loop (pre-scaled)
    float dv = dis[node];
    float4 bb = ((const float4*)b1v)[j];
    float4 r = make_float4(fmaf(dv, aA.x, bb.x), fmaf(dv, aA.y, bb.y),
                           fmaf(dv, aA.z, bb.z), fmaf(dv, aA.w, bb.w));
    r.x = fmaxf(r.x, 0.f); r.y = fmaxf(r.y, 0.f);
    r.z = fmaxf(r.z, 0.f); r.w = fmaxf(r.w, 0.f);
    int nl = t >> 2;
    h1s[nl * 17 + 4 * j + 0] = r.x;
    h1s[nl * 17 + 4 * j + 1] = r.y;
    h1s[nl * 17 + 4 * j + 2] = r.z;
    h1s[nl * 17 + 4 * j + 3] = r.w;
    __syncthreads();
    // mm2: quad j of dis * (h1 @ W2)
    float4 acc = make_float4(0.f, 0.f, 0.f, 0.f);
#pragma unroll
    for (int kk = 0; kk < 16; ++kk) {
        float hv = h1s[nl * 17 + kk];
        float4 wv = ((const float4*)&W2l[kk * 16])[j];
        acc.x = fmaf(hv, wv.x, acc.x);
        acc.y = fmaf(hv, wv.y, acc.y);
        acc.z = fmaf(hv, wv.z, acc.z);
        acc.w = fmaf(hv, wv.w, acc.w);
    }
    out2[(long)node * 4 + j] = make_float4(acc.x * dv, acc.y * dv,
                                           acc.z * dv, acc.w * dv);
}

// Layer-2 gather + relu + FUSED mm3 + scale: writes hws3 (1 float/node).
__global__ __launch_bounds__(256) void k_g16b(
    const int2* __restrict__ odn, const unsigned* __restrict__ csr,
    const float* __restrict__ dis, const float4* __restrict__ tab,
    const float* __restrict__ b2v, const float* __restrict__ W3,
    float* __restrict__ hws3) {
    int t = threadIdx.x;
    int node = blockIdx.x * 64 + (t >> 2);
    int j = t & 3;
    int2 od = odn[node];
    int s0 = od.x, dg = od.y;
    float4 aA = make_float4(0.f, 0.f, 0.f, 0.f);
    float4 aB = make_float4(0.f, 0.f, 0.f, 0.f);
    int k = 0;
    for (; k + 8 <= dg; k += 8) {
        uint4 eL = *(const uint4*)(csr + s0 + k);
        uint4 eH = *(const uint4*)(csr + s0 + k + 4);
        f4add(aA, tab[eL.x * 4 + j]);
        f4add(aB, tab[eH.x * 4 + j]);
        f4add(aA, tab[eL.y * 4 + j]);
        f4add(aB, tab[eH.y * 4 + j]);
        f4add(aA, tab[eL.z * 4 + j]);
        f4add(aB, tab[eH.z * 4 + j]);
        f4add(aA, tab[eL.w * 4 + j]);
        f4add(aB, tab[eH.w * 4 + j]);
    }
    if (k + 4 <= dg) {
        uint4 e = *(const uint4*)(csr + s0 + k);
        f4add(aA, tab[e.x * 4 + j]);
        f4add(aB, tab[e.y * 4 + j]);
        f4add(aA, tab[e.z * 4 + j]);
        f4add(aB, tab[e.w * 4 + j]);
        k += 4;
    }
    for (; k < dg; ++k)
        f4add(aA, tab[csr[s0 + k] * 4 + j]);
    f4add(aA, aB);
    f4add(aA, tab[node * 4 + j]);               // self-loop (pre-scaled)
    float dv = dis[node];
    float4 bb = ((const float4*)b2v)[j];
    float4 r = make_float4(fmaf(dv, aA.x, bb.x), fmaf(dv, aA.y, bb.y),
                           fmaf(dv, aA.z, bb.z), fmaf(dv, aA.w, bb.w));
    r.x = fmaxf(r.x, 0.f); r.y = fmaxf(r.y, 0.f);
    r.z = fmaxf(r.z, 0.f); r.w = fmaxf(r.w, 0.f);
    // mm3: dot(h2, W3), quad j partial -> 4-lane reduce
    float4 w3 = ((const float4*)W3)[j];
    float pd = r.x * w3.x + r.y * w3.y + r.z * w3.z + r.w * w3.w;
    pd += __shfl_xor(pd, 1, 4);
    pd += __shfl_xor(pd, 2, 4);
    if (j == 0) hws3[node] = pd * dv;
}

// Layer-3 gather, 1 channel from the 800KB pre-scaled table (L2-resident).
__global__ __launch_bounds__(256) void k_g1(
    const int2* __restrict__ odn, const unsigned* __restrict__ csr,
    const float* __restrict__ dis, const float* __restrict__ hws3,
    const float* __restrict__ b, float* __restrict__ out, int n) {
    int t = threadIdx.x;
    int node = blockIdx.x * 16 + (t >> 4);
    int ln = t & 15;
    if (node >= n) return;
    int2 od = odn[node];
    int s0 = od.x, dg = od.y;
    float acc = 0.f;
    for (int k = ln; k < dg; k += 16)
        acc += hws3[csr[s0 + k]];
#pragma unroll
    for (int o = 8; o >= 1; o >>= 1) acc += __shfl_down(acc, o, 16);
    if (ln == 0)
        out[node] = fmaf(dis[node], acc + hws3[node], b[0]);
}

extern "C" void kernel_launch(void* const* d_in, const int* in_sizes, int n_in,
                              void* d_out, int out_size, void* d_ws, size_t ws_size,
                              hipStream_t stream) {
    const float* x  = (const float*)d_in[0];
    const int*   ew = (const int*)d_in[1];
    const float* W1 = (const float*)d_in[2];
    const float* b1 = (const float*)d_in[3];
    const float* W2 = (const float*)d_in[4];
    const float* b2 = (const float*)d_in[5];
    const float* W3 = (const float*)d_in[6];
    const float* b3 = (const float*)d_in[7];
    float* out = (float*)d_out;

    // Workspace (4-byte words), ~90 MB. stage/csr/bufA/bufB all disjoint
    // (fused kernel writes stage and bufA concurrently).
    unsigned* stage = (unsigned*)d_ws;               // NCB*CAP = 7,225,344
    unsigned* csr   = stage + (long)NCB * CAP;       // 7,225,344
    int*      gcur  = (int*)(csr + (long)NCB * CAP); // 256
    int*      flag  = gcur + 256;                    // 16
    int2*     odn   = (int2*)(flag + 16);            // 200,704 int2
    float*    dis   = (float*)(odn + 200704);        // 200,704
    float4*   bufA  = (float4*)(dis + 200704);       // 4*200,064 float4 (hws1 / hws3)
    float4*   bufB  = bufA + 4 * 200064;             // 4*200,064 float4 (hws2)

    const int n = NN;
    const long e = EE;
    int gb = n / 64;            // 3125, exact
    int g1b = n / 16;           // 12500, exact

    k_detect<<<1, 256, 0, stream>>>(ew, flag, gcur);
    // partition ∥ layer-1 matmul (independent; roles interleaved by parity)
    k_fused<<<2 * NTILE, 256, 0, stream>>>(ew, flag, gcur, stage, x, W1, bufA, e, n);
    // counting sort + metadata + dis-scale of hw1
    k_sortB<<<NCB, 1024, 0, stream>>>(stage, gcur, dis, odn, csr, bufA, n);
    // layer-1 aggregate + relu + mm2 (fused) -> hws2
    k_g16a<<<gb, 256, 0, stream>>>(odn, csr, dis, bufA, b1, W2, bufB);
    // layer-2 aggregate + relu + mm3 (fused) -> hws3
    k_g16b<<<gb, 256, 0, stream>>>(odn, csr, dis, bufB, b2, W3, (float*)bufA);
    // layer-3 aggregate -> out
    k_g1<<<g1b, 256, 0, stream>>>(odn, csr, dis, (const float*)bufA, b3, out, n);
}

// Round 16
// 433.788 us; speedup vs baseline: 1.2121x; 1.0142x over previous
//
#include <hip/hip_runtime.h>

#define NN 200000
#define EE 6400000L
#define NCB 196          // coarse buckets of 1024 nodes
#define CAP 36864        // fixed bucket capacity; mean 32653 + 6σ + pad < CAP
#define TILE 8192
#define NTILE 782        // ceil(6400000/8192)

__device__ inline void f4add(float4& a, const float4 v) {
    a.x += v.x; a.y += v.y; a.z += v.z; a.w += v.w;
}

// ---------------------------------------------------------------------------
// Edge-index dtype hedge (int64 vs int32): if int64 with values < 2^31, every
// odd 32-bit word is zero. flag=1 -> int64 (word idx = elem<<1), 0 -> int32.
// Also initializes the per-bucket segment cursors gcur[b] = b*CAP.
// ---------------------------------------------------------------------------
__global__ void k_detect(const int* __restrict__ w, int* __restrict__ flag,
                         int* __restrict__ gcur) {
    __shared__ int any;
    if (threadIdx.x == 0) any = 0;
    __syncthreads();
    int found = 0;
    for (int i = threadIdx.x; i < 8192; i += 256)
        if (w[2 * i + 1] != 0) found = 1;
    if (found) atomicOr(&any, 1);
    if (threadIdx.x < NCB) gcur[threadIdx.x] = threadIdx.x * CAP;
    __syncthreads();
    if (threadIdx.x == 0) flag[0] = any ? 0 : 1;
}

// Partition into coarse buckets with tile-exclusive segments (fixed capacity).
// stage entry: src[17:0] | local_dst[27:18]
__global__ __launch_bounds__(256) void k_passA(
    const int* __restrict__ ew, const int* __restrict__ flag,
    int* __restrict__ gcur, unsigned* __restrict__ stage, long e) {
    __shared__ unsigned lv[TILE];
    __shared__ unsigned char lb[TILE];
    __shared__ int lh[NCB], lseg[NCB], lcur[NCB];
    for (int i = threadIdx.x; i < NCB; i += 256) { lh[i] = 0; lcur[i] = 0; }
    __syncthreads();
    long t0 = (long)blockIdx.x * TILE;
    int cnt = (int)min((long)TILE, e - t0);
    int shift = *flag;
    for (int i = threadIdx.x; i < cnt; i += 256) {
        int s = ew[(t0 + i) << shift];
        int d = ew[(EE + t0 + i) << shift];
        int b = d >> 10;
        lv[i] = (unsigned)s | ((unsigned)(d & 1023) << 18);
        lb[i] = (unsigned char)b;
        atomicAdd(&lh[b], 1);
    }
    __syncthreads();
    for (int i = threadIdx.x; i < NCB; i += 256)
        if (lh[i]) lseg[i] = atomicAdd(&gcur[i], lh[i]);
    __syncthreads();
    for (int i = threadIdx.x; i < cnt; i += 256) {
        int b = lb[i];
        int r = atomicAdd(&lcur[b], 1);
        stage[lseg[b] + r] = lv[i];
    }
}

// Per-bucket counting sort: stage (bucket-grouped) -> csr (node-grouped, src).
// Node segments padded to 4-entry (16B) alignment for uint4 csr loads.
// Emits odn = {offset, degree} and dis.
__global__ __launch_bounds__(1024) void k_sortB(
    const unsigned* __restrict__ stage, const int* __restrict__ gcur,
    float* __restrict__ dis, int2* __restrict__ odn,
    unsigned* __restrict__ csr, int n) {
    __shared__ int cnt[1024];
    __shared__ int cur[1024];
    __shared__ int wsum[16];
    int t = threadIdx.x, B = blockIdx.x;
    cnt[t] = 0;
    __syncthreads();
    int s0 = B * CAP, s1 = gcur[B];
    for (int i = s0 + t; i < s1; i += 1024)
        atomicAdd(&cnt[stage[i] >> 18], 1);
    __syncthreads();
    int c = cnt[t];
    int pc = (c + 3) & ~3;              // pad to 4 entries (16B) for uint4 loads
    int lane = t & 63, w = t >> 6;
    int s = pc;
#pragma unroll
    for (int o = 1; o < 64; o <<= 1) {
        int u = __shfl_up(s, o, 64);
        if (lane >= o) s += u;
    }
    if (lane == 63) wsum[w] = s;
    __syncthreads();
    int add = 0;
    for (int k = 0; k < w; ++k) add += wsum[k];
    int excl = s - pc + add;
    cur[t] = excl;
    int node = B * 1024 + t;
    if (node < n) {
        odn[node] = make_int2(s0 + excl, c);
        dis[node] = rsqrtf((float)(c + 1));
    }
    __syncthreads();
    for (int i = s0 + t; i < s1; i += 1024) {
        unsigned v = stage[i];
        int pos = s0 + atomicAdd(&cur[v >> 18], 1);
        csr[pos] = v & 0x3FFFF;
    }
}

// Layer 1 matmul: hws = dis ⊙ (x @ W1), row-major float4 quads.
__global__ __launch_bounds__(256) void k_mm1(
    const float* __restrict__ x, const float* __restrict__ W,
    const float* __restrict__ dis, float4* __restrict__ outr, int n) {
    __shared__ float Wl[256 * 16];
    int t = threadIdx.x;
#pragma unroll
    for (int i = 0; i < 4; ++i)
        ((float4*)Wl)[t + i * 256] = ((const float4*)W)[t + i * 256];
    __syncthreads();

    int node = blockIdx.x * 256 + t;
    if (node >= n) return;

    const float4* xr = (const float4*)(x + (long)node * 256);
    float acc[16];
#pragma unroll
    for (int o = 0; o < 16; ++o) acc[o] = 0.f;

#pragma unroll 8
    for (int kk = 0; kk < 64; ++kk) {
        float4 xv = xr[kk];
#pragma unroll
        for (int q = 0; q < 4; ++q) {
            float xs = (q == 0) ? xv.x : (q == 1) ? xv.y : (q == 2) ? xv.z : xv.w;
            const float4* wr = (const float4*)&Wl[(kk * 4 + q) * 16];
#pragma unroll
            for (int oo = 0; oo < 4; ++oo) {
                float4 wv = wr[oo];
                acc[oo * 4 + 0] = fmaf(xs, wv.x, acc[oo * 4 + 0]);
                acc[oo * 4 + 1] = fmaf(xs, wv.y, acc[oo * 4 + 1]);
                acc[oo * 4 + 2] = fmaf(xs, wv.z, acc[oo * 4 + 2]);
                acc[oo * 4 + 3] = fmaf(xs, wv.w, acc[oo * 4 + 3]);
            }
        }
    }
    float dv = dis[node];
#pragma unroll
    for (int q = 0; q < 4; ++q)
        outr[node * 4 + q] = make_float4(acc[q * 4] * dv, acc[q * 4 + 1] * dv,
                                         acc[q * 4 + 2] * dv, acc[q * 4 + 3] * dv);
}

// Layer-1 gather + relu + FUSED mm2 + scale. 4 lanes/node, 64 nodes/block
// (grid exactly n/64 -> barrier-safe). Gather: lane-uniform uint4 csr,
// dual-chunk unroll, full 64B row per node. Epilogue: h1 quad -> LDS
// (stride 17), barrier, each lane computes quad j of dis*(h1@W2).
__global__ __launch_bounds__(256) void k_g16a(
    const int2* __restrict__ odn, const unsigned* __restrict__ csr,
    const float* __restrict__ dis, const float4* __restrict__ tab,
    const float* __restrict__ b1v, const float* __restrict__ W2,
    float4* __restrict__ out2) {
    __shared__ float h1s[64 * 17];
    __shared__ float W2l[256];
    int t = threadIdx.x;
    if (t < 64) ((float4*)W2l)[t] = ((const float4*)W2)[t];
    int node = blockIdx.x * 64 + (t >> 2);
    int j = t & 3;
    int2 od = odn[node];
    int s0 = od.x, dg = od.y;
    float4 aA = make_float4(0.f, 0.f, 0.f, 0.f);
    float4 aB = make_float4(0.f, 0.f, 0.f, 0.f);
    int k = 0;
    for (; k + 8 <= dg; k += 8) {
        uint4 eL = *(const uint4*)(csr + s0 + k);
        uint4 eH = *(const uint4*)(csr + s0 + k + 4);
        f4add(aA, tab[eL.x * 4 + j]);
        f4add(aB, tab[eH.x * 4 + j]);
        f4add(aA, tab[eL.y * 4 + j]);
        f4add(aB, tab[eH.y * 4 + j]);
        f4add(aA, tab[eL.z * 4 + j]);
        f4add(aB, tab[eH.z * 4 + j]);
        f4add(aA, tab[eL.w * 4 + j]);
        f4add(aB, tab[eH.w * 4 + j]);
    }
    if (k + 4 <= dg) {
        uint4 e = *(const uint4*)(csr + s0 + k);
        f4add(aA, tab[e.x * 4 + j]);
        f4add(aB, tab[e.y * 4 + j]);
        f4add(aA, tab[e.z * 4 + j]);
        f4add(aB, tab[e.w * 4 + j]);
        k += 4;
    }
    for (; k < dg; ++k)
        f4add(aA, tab[csr[s0 + k] * 4 + j]);
    f4add(aA, aB);
    f4add(aA, tab[node * 4 + j]);               // self-loop (pre-scaled)
    float dv = dis[node];
    float4 bb = ((const float4*)b1v)[j];
    float4 r = make_float4(fmaf(dv, aA.x, bb.x), fmaf(dv, aA.y, bb.y),
                           fmaf(dv, aA.z, bb.z), fmaf(dv, aA.w, bb.w));
    r.x = fmaxf(r.x, 0.f); r.y = fmaxf(r.y, 0.f);
    r.z = fmaxf(r.z, 0.f); r.w = fmaxf(r.w, 0.f);
    int nl = t >> 2;
    h1s[nl * 17 + 4 * j + 0] = r.x;
    h1s[nl * 17 + 4 * j + 1] = r.y;
    h1s[nl * 17 + 4 * j + 2] = r.z;
    h1s[nl * 17 + 4 * j + 3] = r.w;
    __syncthreads();
    // mm2: quad j of dis * (h1 @ W2)
    float4 acc = make_float4(0.f, 0.f, 0.f, 0.f);
#pragma unroll
    for (int kk = 0; kk < 16; ++kk) {
        float hv = h1s[nl * 17 + kk];
        float4 wv = ((const float4*)&W2l[kk * 16])[j];
        acc.x = fmaf(hv, wv.x, acc.x);
        acc.y = fmaf(hv, wv.y, acc.y);
        acc.z = fmaf(hv, wv.z, acc.z);
        acc.w = fmaf(hv, wv.w, acc.w);
    }
    out2[(long)node * 4 + j] = make_float4(acc.x * dv, acc.y * dv,
                                           acc.z * dv, acc.w * dv);
}

// Layer-2 gather + relu + FUSED mm3 + scale: writes hws3 (1 float/node).
__global__ __launch_bounds__(256) void k_g16b(
    const int2* __restrict__ odn, const unsigned* __restrict__ csr,
    const float* __restrict__ dis, const float4* __restrict__ tab,
    const float* __restrict__ b2v, const float* __restrict__ W3,
    float* __restrict__ hws3) {
    int t = threadIdx.x;
    int node = blockIdx.x * 64 + (t >> 2);
    int j = t & 3;
    int2 od = odn[node];
    int s0 = od.x, dg = od.y;
    float4 aA = make_float4(0.f, 0.f, 0.f, 0.f);
    float4 aB = make_float4(0.f, 0.f, 0.f, 0.f);
    int k = 0;
    for (; k + 8 <= dg; k += 8) {
        uint4 eL = *(const uint4*)(csr + s0 + k);
        uint4 eH = *(const uint4*)(csr + s0 + k + 4);
        f4add(aA, tab[eL.x * 4 + j]);
        f4add(aB, tab[eH.x * 4 + j]);
        f4add(aA, tab[eL.y * 4 + j]);
        f4add(aB, tab[eH.y * 4 + j]);
        f4add(aA, tab[eL.z * 4 + j]);
        f4add(aB, tab[eH.z * 4 + j]);
        f4add(aA, tab[eL.w * 4 + j]);
        f4add(aB, tab[eH.w * 4 + j]);
    }
    if (k + 4 <= dg) {
        uint4 e = *(const uint4*)(csr + s0 + k);
        f4add(aA, tab[e.x * 4 + j]);
        f4add(aB, tab[e.y * 4 + j]);
        f4add(aA, tab[e.z * 4 + j]);
        f4add(aB, tab[e.w * 4 + j]);
        k += 4;
    }
    for (; k < dg; ++k)
        f4add(aA, tab[csr[s0 + k] * 4 + j]);
    f4add(aA, aB);
    f4add(aA, tab[node * 4 + j]);               // self-loop (pre-scaled)
    float dv = dis[node];
    float4 bb = ((const float4*)b2v)[j];
    float4 r = make_float4(fmaf(dv, aA.x, bb.x), fmaf(dv, aA.y, bb.y),
                           fmaf(dv, aA.z, bb.z), fmaf(dv, aA.w, bb.w));
    r.x = fmaxf(r.x, 0.f); r.y = fmaxf(r.y, 0.f);
    r.z = fmaxf(r.z, 0.f); r.w = fmaxf(r.w, 0.f);
    // mm3: dot(h2, W3), quad j partial -> 4-lane reduce
    float4 w3 = ((const float4*)W3)[j];
    float pd = r.x * w3.x + r.y * w3.y + r.z * w3.z + r.w * w3.w;
    pd += __shfl_xor(pd, 1, 4);
    pd += __shfl_xor(pd, 2, 4);
    if (j == 0) hws3[node] = pd * dv;
}

// Layer-3 gather, 1 channel from the 800KB pre-scaled table (L2-resident).
__global__ __launch_bounds__(256) void k_g1(
    const int2* __restrict__ odn, const unsigned* __restrict__ csr,
    const float* __restrict__ dis, const float* __restrict__ hws3,
    const float* __restrict__ b, float* __restrict__ out, int n) {
    int t = threadIdx.x;
    int node = blockIdx.x * 16 + (t >> 4);
    int ln = t & 15;
    if (node >= n) return;
    int2 od = odn[node];
    int s0 = od.x, dg = od.y;
    float acc = 0.f;
    for (int k = ln; k < dg; k += 16)
        acc += hws3[csr[s0 + k]];
#pragma unroll
    for (int o = 8; o >= 1; o >>= 1) acc += __shfl_down(acc, o, 16);
    if (ln == 0)
        out[node] = fmaf(dis[node], acc + hws3[node], b[0]);
}

extern "C" void kernel_launch(void* const* d_in, const int* in_sizes, int n_in,
                              void* d_out, int out_size, void* d_ws, size_t ws_size,
                              hipStream_t stream) {
    const float* x  = (const float*)d_in[0];
    const int*   ew = (const int*)d_in[1];
    const float* W1 = (const float*)d_in[2];
    const float* b1 = (const float*)d_in[3];
    const float* W2 = (const float*)d_in[4];
    const float* b2 = (const float*)d_in[5];
    const float* W3 = (const float*)d_in[6];
    const float* b3 = (const float*)d_in[7];
    float* out = (float*)d_out;

    // Workspace (4-byte words), ~90 MB.
    unsigned* stage = (unsigned*)d_ws;               // NCB*CAP = 7,225,344
    unsigned* csr   = stage + (long)NCB * CAP;       // 7,225,344
    int*      gcur  = (int*)(csr + (long)NCB * CAP); // 256
    int*      flag  = gcur + 256;                    // 16
    int2*     odn   = (int2*)(flag + 16);            // 200,704 int2
    float*    dis   = (float*)(odn + 200704);        // 200,704
    float4*   bufA  = (float4*)(dis + 200704);       // 4*200,064 float4 (hws1 / hws3)
    float4*   bufB  = bufA + 4 * 200064;             // 4*200,064 float4 (hws2)

    const int n = NN;
    const long e = EE;
    int nb = (n + 255) / 256;   // 782
    int gb = n / 64;            // 3125, exact
    int g1b = n / 16;           // 12500, exact

    k_detect<<<1, 256, 0, stream>>>(ew, flag, gcur);
    // partition -> counting sort (metadata) -> layer-1 matmul (dis-scaled)
    k_passA<<<NTILE, 256, 0, stream>>>(ew, flag, gcur, stage, e);
    k_sortB<<<NCB, 1024, 0, stream>>>(stage, gcur, dis, odn, csr, n);
    k_mm1<<<nb, 256, 0, stream>>>(x, W1, dis, bufA, n);
    // layer-1 aggregate + relu + mm2 (fused) -> hws2
    k_g16a<<<gb, 256, 0, stream>>>(odn, csr, dis, bufA, b1, W2, bufB);
    // layer-2 aggregate + relu + mm3 (fused) -> hws3
    k_g16b<<<gb, 256, 0, stream>>>(odn, csr, dis, bufB, b2, W3, (float*)bufA);
    // layer-3 aggregate -> out
    k_g1<<<g1b, 256, 0, stream>>>(odn, csr, dis, (const float*)bufA, b3, out, n);
}